// Round 3
// baseline (226.782 us; speedup 1.0000x reference)
//
#include <hip/hip_runtime.h>
#include <hip/hip_bf16.h>

// Problem constants: B=4,S=2048 -> T=8192 tokens, H=1024, E=8, TOP_K=2
#define H 1024
#define NEXP 8
#define T_TOK 8192
#define CAP 8192
#define TM 128
#define TN 128
#define CNTSTRIDE 32
// prep grid: 4096 blocks; even = We-transpose tile (2048), odd = routing (2048).
// Interleaving keeps both streams co-resident (R9: was 2048 transpose then 512 routing,
// which serialized into two phases with a 2-wave/SIMD latency-bound routing tail).
#define NPREP 4096

typedef __bf16 bf16x8 __attribute__((ext_vector_type(8)));
typedef __bf16 bf16x4 __attribute__((ext_vector_type(4)));
typedef float f32x4 __attribute__((ext_vector_type(4)));

__device__ __forceinline__ void async16(void* lds, const void* g) {
    __builtin_amdgcn_global_load_lds(
        (const __attribute__((address_space(1))) void*)g,
        (__attribute__((address_space(3))) void*)lds, 16, 0, 0);
}

// ---------------- prep: interleaved We-transpose (even blocks) + routing (odd blocks) ----------
__global__ __launch_bounds__(256) void moe_prep(
    const float* __restrict__ We, __bf16* __restrict__ WeT,
    const float* __restrict__ x, const float* __restrict__ Wg,
    __bf16* __restrict__ Xb, int* __restrict__ cnt,
    int* __restrict__ ltok,
    int* __restrict__ tsel, float* __restrict__ tgate) {
    __shared__ __align__(16) char smem[64 * 65 * 4];
    const int tid = threadIdx.x;

    if ((blockIdx.x & 1) == 0) {
        // ---- We (E,h,d) fp32 -> WeT (E,d,h) bf16, 64x64 tile ----
        float (*t)[65] = (float(*)[65])smem;   // stride 65
        const int tt = blockIdx.x >> 1;
        const int e  = tt >> 8;
        const int d0 = ((tt >> 4) & 15) * 64;
        const int h0 = (tt & 15) * 64;
        const int tx = tid & 15;
        const int ty = tid >> 4;
        const float* src = We + ((size_t)e << 20);
        __bf16* dst = WeT + ((size_t)e << 20);
#pragma unroll
        for (int p = 0; p < 4; ++p) {
            const int row = p * 16 + ty;
            const float4 v = *(const float4*)(src + (size_t)(h0 + row) * H + d0 + tx * 4);
            t[row][tx * 4 + 0] = v.x; t[row][tx * 4 + 1] = v.y;
            t[row][tx * 4 + 2] = v.z; t[row][tx * 4 + 3] = v.w;
        }
        __syncthreads();
        // phase 2: 512 bf16x8 row-chunks (drow, seg); 2 per thread. LDS read bank check:
        // word addr = (seg*8+i)*65 + drow; across 64 lanes (seg,drow) -> (8s+d+i)&31,
        // 8s+d covers 0..63 distinct -> 2-way alias only (free, m136). Stores 16B/lane.
#pragma unroll
        for (int qq = 0; qq < 2; ++qq) {
            const int q = tid + qq * 256;
            const int drow = q >> 3;
            const int seg  = q & 7;
            bf16x8 o;
#pragma unroll
            for (int i = 0; i < 8; ++i) o[i] = (__bf16)t[seg * 8 + i][drow];
            *(bf16x8*)(dst + (size_t)(d0 + drow) * H + h0 + seg * 8) = o;
        }
        return;
    }

    // ---- routing: one token per WAVE (4 tokens/block, 2048 blocks) ----
    int*   sE    = (int*)smem;            // 8 ints
    float* sG    = (float*)(smem + 64);   // 8 floats
    int*   lcnt  = (int*)(smem + 128);    // 8
    int*   lbase = (int*)(smem + 160);    // 8
    int*   lslot = (int*)(smem + 192);    // 8
    const int lane = tid & 63;
    const int wave = tid >> 6;
    const int base = (blockIdx.x >> 1) * 4;
    const int t = base + wave;

    const float* xr  = x  + (size_t)t * H;
    __bf16*      xbr = Xb + (size_t)t * H;

    // 4 independent x loads in flight (short dep chains; TLP hides the rest)
    const float4 xv0 = *(const float4*)(xr + 0   + lane * 4);
    const float4 xv1 = *(const float4*)(xr + 256 + lane * 4);
    const float4 xv2 = *(const float4*)(xr + 512 + lane * 4);
    const float4 xv3 = *(const float4*)(xr + 768 + lane * 4);
    const float4 xv[4] = {xv0, xv1, xv2, xv3};

    float a[NEXP];
#pragma unroll
    for (int e = 0; e < NEXP; ++e) a[e] = 0.f;

#pragma unroll
    for (int c = 0; c < 4; ++c) {
        const int h = c * 256 + lane * 4;
        bf16x4 xo;
        xo[0] = (__bf16)xv[c].x; xo[1] = (__bf16)xv[c].y;
        xo[2] = (__bf16)xv[c].z; xo[3] = (__bf16)xv[c].w;
        *(bf16x4*)(xbr + h) = xo;
        const float* wgp = Wg + (size_t)h * NEXP;
        float4 w[8];
#pragma unroll
        for (int r2 = 0; r2 < 8; ++r2) w[r2] = *(const float4*)(wgp + r2 * 4);
        const float xc[4] = {xv[c].x, xv[c].y, xv[c].z, xv[c].w};
#pragma unroll
        for (int i = 0; i < 4; ++i) {
            a[0] += xc[i] * w[i * 2].x; a[1] += xc[i] * w[i * 2].y;
            a[2] += xc[i] * w[i * 2].z; a[3] += xc[i] * w[i * 2].w;
            a[4] += xc[i] * w[i * 2 + 1].x; a[5] += xc[i] * w[i * 2 + 1].y;
            a[6] += xc[i] * w[i * 2 + 1].z; a[7] += xc[i] * w[i * 2 + 1].w;
        }
    }

#pragma unroll
    for (int e = 0; e < NEXP; ++e) {
#pragma unroll
        for (int off = 32; off > 0; off >>= 1)
            a[e] += __shfl_xor(a[e], off, 64);
    }
    int i0 = 0;
#pragma unroll
    for (int e = 1; e < NEXP; ++e) if (a[e] > a[i0]) i0 = e;   // jax tie-break: lowest idx
    int i1 = (i0 == 0) ? 1 : 0;
#pragma unroll
    for (int e = 0; e < NEXP; ++e) if (e != i0 && a[e] > a[i1]) i1 = e;
    const float ex = __expf(a[i1] - a[i0]);
    const float g0 = 1.f / (1.f + ex);
    const float g1 = ex / (1.f + ex);
    if (lane == 0) {
        sE[wave * 2] = i0; sE[wave * 2 + 1] = i1;
        sG[wave * 2] = g0; sG[wave * 2 + 1] = g1;
    }
    if (tid < NEXP) lcnt[tid] = 0;
    __syncthreads();
    if (tid < 8) lslot[tid] = atomicAdd(&lcnt[sE[tid]], 1);
    __syncthreads();
    if (tid < NEXP) lbase[tid] = lcnt[tid] ? atomicAdd(&cnt[tid * CNTSTRIDE], lcnt[tid]) : 0;
    __syncthreads();
    if (tid < 8) {
        const int e = sE[tid];
        const int s = lbase[e] + lslot[tid];
        const int tt2 = base + (tid >> 1);
        ltok[e * CAP + s] = tt2;
        tsel[tt2 * 2 + (tid & 1)]  = e * CAP + s;
        tgate[tt2 * 2 + (tid & 1)] = sG[tid];
    }
}

// ---------------- grouped GEMM: 128x128 tile, BK=64 (two BK=32 panels), bf16 MFMA ----------------
// R6 structure (proven ~55-56us / ~620 TF): 33KB LDS -> ~4 blocks/CU; inter-block overlap
// (m114) beats the 1-block/CU hand pipeline tried in R7 (78us).
// XCD-pinned swizzle: blockIdx&7 = expert keeps each expert's 2MB B-panel L2-resident.
__global__ __launch_bounds__(256) void moe_gemm(
    const __bf16* __restrict__ Xb, const __bf16* __restrict__ WeT,
    const float* __restrict__ be, const int* __restrict__ cnt,
    const int* __restrict__ ltok,
    __bf16* __restrict__ Eout) {
    const int e  = blockIdx.x & 7;
    const int nt = (blockIdx.x >> 3) & 7;
    const int mt = blockIdx.x >> 6;
    const int ne = cnt[e * CNTSTRIDE];
    const int m0 = mt * TM;
    if (m0 >= ne) return;
    const int n0 = nt * TN;
    int off = 0;
    for (int i2 = 0; i2 < e; ++i2) off += cnt[i2 * CNTSTRIDE];

    __shared__ __align__(16) __bf16 smem[4 * 4096];  // Al|Al2|Bl|Bl2; epilogue: 4 x (64x64)
    __bf16* Al  = smem;
    __bf16* Al2 = smem + 4096;
    __bf16* Bl  = smem + 8192;
    __bf16* Bl2 = smem + 12288;
    __shared__ int tokL[TM];

    const int tid = threadIdx.x;
    const int lane = tid & 63;
    const int wave = tid >> 6;

    if (tid < TM) {
        const int gi = m0 + tid;
        tokL[tid] = (gi < ne) ? ltok[e * CAP + gi] : 0;
    }
    __syncthreads();

    const __bf16* Bt = WeT + ((size_t)e << 20);
    const int qr = lane >> 4;
    const int rr = lane & 15;
    const int wr = (wave >> 1) * 64;
    const int wc = (wave & 1) * 64;

    f32x4 acc[4][4];
    const f32x4 z = {0.f, 0.f, 0.f, 0.f};
#pragma unroll
    for (int i = 0; i < 4; ++i)
#pragma unroll
        for (int j = 0; j < 4; ++j) acc[i][j] = z;

    const int c0 = tid, c1 = tid + 256;
    const int ar0 = c0 >> 2, ak0 = (((c0 & 3) ^ ((c0 >> 3) & 3)) * 8);
    const int ar1 = c1 >> 2, ak1 = (((c1 & 3) ^ ((c1 >> 3) & 3)) * 8);
    const size_t arow0 = (size_t)tokL[ar0] * H;
    const size_t arow1 = (size_t)tokL[ar1] * H;
    const size_t brow0 = (size_t)(n0 + ar0) * H;
    const size_t brow1 = (size_t)(n0 + ar1) * H;

    for (int k0 = 0; k0 < H; k0 += 64) {
        async16(&Al [c0 * 8], Xb + arow0 + k0 + ak0);
        async16(&Al [c1 * 8], Xb + arow1 + k0 + ak1);
        async16(&Al2[c0 * 8], Xb + arow0 + k0 + 32 + ak0);
        async16(&Al2[c1 * 8], Xb + arow1 + k0 + 32 + ak1);
        async16(&Bl [c0 * 8], Bt + brow0 + k0 + ak0);
        async16(&Bl [c1 * 8], Bt + brow1 + k0 + ak1);
        async16(&Bl2[c0 * 8], Bt + brow0 + k0 + 32 + ak0);
        async16(&Bl2[c1 * 8], Bt + brow1 + k0 + 32 + ak1);
        __syncthreads();
        {
            bf16x8 af[4], bfr[4];
#pragma unroll
            for (int i = 0; i < 4; ++i) {
                const int ra = wr + i * 16 + rr;
                af[i] = *(const bf16x8*)&Al[ra * 32 + ((qr ^ ((ra >> 1) & 3)) * 8)];
            }
#pragma unroll
            for (int j = 0; j < 4; ++j) {
                const int rb = wc + j * 16 + rr;
                bfr[j] = *(const bf16x8*)&Bl[rb * 32 + ((qr ^ ((rb >> 1) & 3)) * 8)];
            }
#pragma unroll
            for (int i = 0; i < 4; ++i)
#pragma unroll
                for (int j = 0; j < 4; ++j)
                    acc[i][j] = __builtin_amdgcn_mfma_f32_16x16x32_bf16(af[i], bfr[j], acc[i][j], 0, 0, 0);
        }
        {
            bf16x8 af[4], bfr[4];
#pragma unroll
            for (int i = 0; i < 4; ++i) {
                const int ra = wr + i * 16 + rr;
                af[i] = *(const bf16x8*)&Al2[ra * 32 + ((qr ^ ((ra >> 1) & 3)) * 8)];
            }
#pragma unroll
            for (int j = 0; j < 4; ++j) {
                const int rb = wc + j * 16 + rr;
                bfr[j] = *(const bf16x8*)&Bl2[rb * 32 + ((qr ^ ((rb >> 1) & 3)) * 8)];
            }
#pragma unroll
            for (int i = 0; i < 4; ++i)
#pragma unroll
                for (int j = 0; j < 4; ++j)
                    acc[i][j] = __builtin_amdgcn_mfma_f32_16x16x32_bf16(af[i], bfr[j], acc[i][j], 0, 0, 0);
        }
        __syncthreads();   // also protects smem reuse by the epilogue on the last iter
    }

    float bev[4];
#pragma unroll
    for (int j = 0; j < 4; ++j) bev[j] = be[e * H + n0 + wc + j * 16 + rr];

    // ---- epilogue: per-wave 64x64 LDS stage (XOR col swizzle), then full-line bf16x8 stores ----
    __bf16* Cw = smem + wave * 4096;
#pragma unroll
    for (int i = 0; i < 4; ++i) {
#pragma unroll
        for (int reg = 0; reg < 4; ++reg) {
            const int row = i * 16 + qr * 4 + reg;      // C/D layout: col=lane&15, row=quad*4+reg
            const int key = (row & 7) * 8;
#pragma unroll
            for (int j = 0; j < 4; ++j) {
                const int c = j * 16 + rr;
                Cw[row * 64 + (c ^ key)] = (__bf16)(acc[i][j][reg] + bev[j]);
            }
        }
    }
    const int lrr = lane & 7, lrg = lane >> 3;
#pragma unroll
    for (int p = 0; p < 8; ++p) {
        const int row = p * 8 + lrg;
        const int rglob = m0 + wr + row;
        if (rglob < ne) {
            const int idx8 = ((lrr ^ (row & 7)) * 8);
            const bf16x8 v = *(const bf16x8*)&Cw[row * 64 + idx8];
            *(bf16x8*)(Eout + (size_t)(off + rglob) * H + n0 + wc + lrr * 8) = v;
        }
    }
}

// ---------------- combine: wave per token, out[t] = g0*row0 + g1*row1 ----------------
__global__ __launch_bounds__(256) void moe_combine(
    const __bf16* __restrict__ Eout, const int* __restrict__ cnt,
    const int* __restrict__ tsel, const float* __restrict__ tgate,
    float* __restrict__ out) {
    __shared__ int offs[NEXP];
    if (threadIdx.x < NEXP) {
        int o = 0;
        for (int i = 0; i < (int)threadIdx.x; ++i) o += cnt[i * CNTSTRIDE];
        offs[threadIdx.x] = o;
    }
    __syncthreads();
    const int wave = threadIdx.x >> 6, lane = threadIdx.x & 63;
    const int t = blockIdx.x * 4 + wave;
    const int sel0 = tsel[t * 2],  sel1 = tsel[t * 2 + 1];
    const float g0 = tgate[t * 2], g1  = tgate[t * 2 + 1];
    const int e0 = sel0 >> 13, s0 = sel0 & (CAP - 1);
    const int e1 = sel1 >> 13, s1 = sel1 & (CAP - 1);
    const __bf16* r0 = Eout + (size_t)(offs[e0] + s0) * H;
    const __bf16* r1 = Eout + (size_t)(offs[e1] + s1) * H;
    float* orow = out + (size_t)t * H;
#pragma unroll
    for (int c = 0; c < 2; ++c) {
        const int d = c * 512 + lane * 8;
        const bf16x8 a = *(const bf16x8*)(r0 + d);
        const bf16x8 b = *(const bf16x8*)(r1 + d);
        float4 o0, o1;
        o0.x = g0 * (float)a[0] + g1 * (float)b[0];
        o0.y = g0 * (float)a[1] + g1 * (float)b[1];
        o0.z = g0 * (float)a[2] + g1 * (float)b[2];
        o0.w = g0 * (float)a[3] + g1 * (float)b[3];
        o1.x = g0 * (float)a[4] + g1 * (float)b[4];
        o1.y = g0 * (float)a[5] + g1 * (float)b[5];
        o1.z = g0 * (float)a[6] + g1 * (float)b[6];
        o1.w = g0 * (float)a[7] + g1 * (float)b[7];
        *(float4*)(orow + d)     = o0;
        *(float4*)(orow + d + 4) = o1;
    }
}

extern "C" void kernel_launch(void* const* d_in, const int* in_sizes, int n_in,
                              void* d_out, int out_size, void* d_ws, size_t ws_size,
                              hipStream_t stream) {
    const float* x  = (const float*)d_in[0];
    const float* Wg = (const float*)d_in[1];
    const float* We = (const float*)d_in[2];
    const float* be = (const float*)d_in[3];
    float* out = (float*)d_out;

    char* ws = (char*)d_ws;
    __bf16* Xb   = (__bf16*)ws;
    __bf16* WeT  = (__bf16*)(ws + ((size_t)16 << 20));
    __bf16* Eout = (__bf16*)(ws + ((size_t)32 << 20));
    char*   meta = ws + ((size_t)64 << 20);
    int*    cnt  = (int*)meta;
    int*    ltok = (int*)(meta + 1024);
    int*    tsel = (int*)(meta + 1024 + (size_t)NEXP * CAP * 8);
    float*  tgat = (float*)(meta + 1024 + (size_t)NEXP * CAP * 8 + (size_t)T_TOK * 8);

    hipMemsetAsync(cnt, 0, NEXP * CNTSTRIDE * sizeof(int), stream);

    moe_prep<<<NPREP, 256, 0, stream>>>(We, WeT, x, Wg, Xb, cnt, ltok, tsel, tgat);
    moe_gemm<<<8 * 8 * (T_TOK / TM), 256, 0, stream>>>(Xb, WeT, be, cnt, ltok, Eout);
    moe_combine<<<T_TOK / 4, 256, 0, stream>>>(Eout, cnt, tsel, tgat, out);
}

// Round 4
// 200.414 us; speedup vs baseline: 1.1316x; 1.1316x over previous
//
#include <hip/hip_runtime.h>
#include <hip/hip_bf16.h>

// Problem constants: B=4,S=2048 -> T=8192 tokens, H=1024, E=8, TOP_K=2
#define H 1024
#define NEXP 8
#define T_TOK 8192
#define CAP 8192
#define TM 128
#define TN 128
#define CNTSTRIDE 32

typedef __bf16 bf16x8 __attribute__((ext_vector_type(8)));
typedef __bf16 bf16x4 __attribute__((ext_vector_type(4)));
typedef float f32x4 __attribute__((ext_vector_type(4)));

__device__ __forceinline__ void async16(void* lds, const void* g) {
    __builtin_amdgcn_global_load_lds(
        (const __attribute__((address_space(1))) void*)g,
        (__attribute__((address_space(3))) void*)lds, 16, 0, 0);
}

// ---------------- transpose: We (E,h,d) fp32 -> WeT (E,d,h) bf16, 64x64 tiles ----------------
// Split out from fused prep (R10) for counter attribution. Reads: 16 rows x 256B full
// lines per instr; writes: 8 rows x 128B full lines per instr (bf16x8, R9's fix).
__global__ __launch_bounds__(256) void moe_transpose(
    const float* __restrict__ We, __bf16* __restrict__ WeT) {
    __shared__ __align__(16) float t[64][65];   // stride 65: 2-way alias only (free, m136)
    const int tid = threadIdx.x;
    const int tt = blockIdx.x;
    const int e  = tt >> 8;
    const int d0 = ((tt >> 4) & 15) * 64;
    const int h0 = (tt & 15) * 64;
    const int tx = tid & 15;
    const int ty = tid >> 4;
    const float* src = We + ((size_t)e << 20);
    __bf16* dst = WeT + ((size_t)e << 20);
#pragma unroll
    for (int p = 0; p < 4; ++p) {
        const int row = p * 16 + ty;
        const float4 v = *(const float4*)(src + (size_t)(h0 + row) * H + d0 + tx * 4);
        t[row][tx * 4 + 0] = v.x; t[row][tx * 4 + 1] = v.y;
        t[row][tx * 4 + 2] = v.z; t[row][tx * 4 + 3] = v.w;
    }
    __syncthreads();
    // 512 bf16x8 chunks (drow, seg), 2/thread. LDS bank check: word = (seg*8+i)*65+drow;
    // across 64 lanes -> 2-way alias only.
#pragma unroll
    for (int qq = 0; qq < 2; ++qq) {
        const int q = tid + qq * 256;
        const int drow = q >> 3;
        const int seg  = q & 7;
        bf16x8 o;
#pragma unroll
        for (int i = 0; i < 8; ++i) o[i] = (__bf16)t[seg * 8 + i][drow];
        *(bf16x8*)(dst + (size_t)(d0 + drow) * H + h0 + seg * 8) = o;
    }
}

// ---------------- route: logits, top-2, gates, compaction; fused x -> bf16 cast -------------
// R10: all 16 x-row loads issued UPFRONT (independent, in flight together) instead of 4
// serial {load -> 128 FMA} dependency chains per wave (the R8/R9 latency defect).
// Wg slice loaded once per c, reused across the wave's 4 tokens. 512 blocks, 16 tok/block.
__global__ __launch_bounds__(256) void moe_route(
    const float* __restrict__ x, const float* __restrict__ Wg,
    __bf16* __restrict__ Xb, int* __restrict__ cnt,
    int* __restrict__ ltok,
    int* __restrict__ tsel, float* __restrict__ tgate) {
    __shared__ int   sE[32];
    __shared__ float sG[32];
    __shared__ int   lcnt[NEXP], lbase[NEXP], lslot[32];
    const int tid  = threadIdx.x;
    const int lane = tid & 63;
    const int wave = tid >> 6;
    const int base = blockIdx.x * 16;

    // ---- upfront loads: 16 independent float4s (4 tokens x 4 chunks) ----
    float4 xv[4][4];
#pragma unroll
    for (int tk = 0; tk < 4; ++tk) {
        const float* xr = x + (size_t)(base + wave * 4 + tk) * H;
#pragma unroll
        for (int c = 0; c < 4; ++c)
            xv[tk][c] = *(const float4*)(xr + c * 256 + lane * 4);
    }

    float a[4][NEXP];
#pragma unroll
    for (int tk = 0; tk < 4; ++tk)
#pragma unroll
        for (int e = 0; e < NEXP; ++e) a[tk][e] = 0.f;

#pragma unroll
    for (int c = 0; c < 4; ++c) {
        const float* wgp = Wg + (size_t)(c * 256 + lane * 4) * NEXP;
        float4 w[8];
#pragma unroll
        for (int r = 0; r < 8; ++r) w[r] = *(const float4*)(wgp + r * 4);
#pragma unroll
        for (int tk = 0; tk < 4; ++tk) {
            const float xc[4] = {xv[tk][c].x, xv[tk][c].y, xv[tk][c].z, xv[tk][c].w};
#pragma unroll
            for (int i = 0; i < 4; ++i) {
                a[tk][0] += xc[i] * w[i * 2].x;     a[tk][1] += xc[i] * w[i * 2].y;
                a[tk][2] += xc[i] * w[i * 2].z;     a[tk][3] += xc[i] * w[i * 2].w;
                a[tk][4] += xc[i] * w[i * 2 + 1].x; a[tk][5] += xc[i] * w[i * 2 + 1].y;
                a[tk][6] += xc[i] * w[i * 2 + 1].z; a[tk][7] += xc[i] * w[i * 2 + 1].w;
            }
        }
    }

    // ---- fused bf16 cast of x (fire-and-forget stores) ----
#pragma unroll
    for (int tk = 0; tk < 4; ++tk) {
        __bf16* xbr = Xb + (size_t)(base + wave * 4 + tk) * H;
#pragma unroll
        for (int c = 0; c < 4; ++c) {
            bf16x4 xo;
            xo[0] = (__bf16)xv[tk][c].x; xo[1] = (__bf16)xv[tk][c].y;
            xo[2] = (__bf16)xv[tk][c].z; xo[3] = (__bf16)xv[tk][c].w;
            *(bf16x4*)(xbr + c * 256 + lane * 4) = xo;
        }
    }

    // ---- reduce + top-2 + gates per token ----
#pragma unroll
    for (int tk = 0; tk < 4; ++tk) {
        const int tl = wave * 4 + tk;
#pragma unroll
        for (int e = 0; e < NEXP; ++e) {
#pragma unroll
            for (int off = 32; off > 0; off >>= 1)
                a[tk][e] += __shfl_xor(a[tk][e], off, 64);
        }
        int i0 = 0;
#pragma unroll
        for (int e = 1; e < NEXP; ++e) if (a[tk][e] > a[tk][i0]) i0 = e;  // jax tie-break: lowest idx
        int i1 = (i0 == 0) ? 1 : 0;
#pragma unroll
        for (int e = 0; e < NEXP; ++e) if (e != i0 && a[tk][e] > a[tk][i1]) i1 = e;
        const float ex = __expf(a[tk][i1] - a[tk][i0]);
        const float g0 = 1.f / (1.f + ex);
        const float g1 = ex / (1.f + ex);
        if (lane == 0) {
            sE[tl * 2] = i0; sE[tl * 2 + 1] = i1;
            sG[tl * 2] = g0; sG[tl * 2 + 1] = g1;
        }
    }
    if (tid < NEXP) lcnt[tid] = 0;
    __syncthreads();
    if (tid < 32) lslot[tid] = atomicAdd(&lcnt[sE[tid]], 1);
    __syncthreads();
    if (tid < NEXP) lbase[tid] = lcnt[tid] ? atomicAdd(&cnt[tid * CNTSTRIDE], lcnt[tid]) : 0;
    __syncthreads();
    if (tid < 32) {
        const int e = sE[tid];
        const int s = lbase[e] + lslot[tid];
        const int t = base + (tid >> 1);
        ltok[e * CAP + s] = t;
        tsel[t * 2 + (tid & 1)]  = e * CAP + s;
        tgate[t * 2 + (tid & 1)] = sG[tid];
    }
}

// ---------------- grouped GEMM: 128x128 tile, BK=64 (two BK=32 panels), bf16 MFMA ----------------
// R6 structure (proven ~55-56us / ~620 TF): 33KB LDS -> ~4 blocks/CU; inter-block overlap
// (m114) beats the 1-block/CU hand pipeline tried in R7 (78us).
// XCD-pinned swizzle: blockIdx&7 = expert keeps each expert's 2MB B-panel L2-resident.
__global__ __launch_bounds__(256) void moe_gemm(
    const __bf16* __restrict__ Xb, const __bf16* __restrict__ WeT,
    const float* __restrict__ be, const int* __restrict__ cnt,
    const int* __restrict__ ltok,
    __bf16* __restrict__ Eout) {
    const int e  = blockIdx.x & 7;
    const int nt = (blockIdx.x >> 3) & 7;
    const int mt = blockIdx.x >> 6;
    const int ne = cnt[e * CNTSTRIDE];
    const int m0 = mt * TM;
    if (m0 >= ne) return;
    const int n0 = nt * TN;
    int off = 0;
    for (int i2 = 0; i2 < e; ++i2) off += cnt[i2 * CNTSTRIDE];

    __shared__ __align__(16) __bf16 smem[4 * 4096];  // Al|Al2|Bl|Bl2; epilogue: 4 x (64x64)
    __bf16* Al  = smem;
    __bf16* Al2 = smem + 4096;
    __bf16* Bl  = smem + 8192;
    __bf16* Bl2 = smem + 12288;
    __shared__ int tokL[TM];

    const int tid = threadIdx.x;
    const int lane = tid & 63;
    const int wave = tid >> 6;

    if (tid < TM) {
        const int gi = m0 + tid;
        tokL[tid] = (gi < ne) ? ltok[e * CAP + gi] : 0;
    }
    __syncthreads();

    const __bf16* Bt = WeT + ((size_t)e << 20);
    const int qr = lane >> 4;
    const int rr = lane & 15;
    const int wr = (wave >> 1) * 64;
    const int wc = (wave & 1) * 64;

    f32x4 acc[4][4];
    const f32x4 z = {0.f, 0.f, 0.f, 0.f};
#pragma unroll
    for (int i = 0; i < 4; ++i)
#pragma unroll
        for (int j = 0; j < 4; ++j) acc[i][j] = z;

    const int c0 = tid, c1 = tid + 256;
    const int ar0 = c0 >> 2, ak0 = (((c0 & 3) ^ ((c0 >> 3) & 3)) * 8);
    const int ar1 = c1 >> 2, ak1 = (((c1 & 3) ^ ((c1 >> 3) & 3)) * 8);
    const size_t arow0 = (size_t)tokL[ar0] * H;
    const size_t arow1 = (size_t)tokL[ar1] * H;
    const size_t brow0 = (size_t)(n0 + ar0) * H;
    const size_t brow1 = (size_t)(n0 + ar1) * H;

    for (int k0 = 0; k0 < H; k0 += 64) {
        async16(&Al [c0 * 8], Xb + arow0 + k0 + ak0);
        async16(&Al [c1 * 8], Xb + arow1 + k0 + ak1);
        async16(&Al2[c0 * 8], Xb + arow0 + k0 + 32 + ak0);
        async16(&Al2[c1 * 8], Xb + arow1 + k0 + 32 + ak1);
        async16(&Bl [c0 * 8], Bt + brow0 + k0 + ak0);
        async16(&Bl [c1 * 8], Bt + brow1 + k0 + ak1);
        async16(&Bl2[c0 * 8], Bt + brow0 + k0 + 32 + ak0);
        async16(&Bl2[c1 * 8], Bt + brow1 + k0 + 32 + ak1);
        __syncthreads();
        {
            bf16x8 af[4], bfr[4];
#pragma unroll
            for (int i = 0; i < 4; ++i) {
                const int ra = wr + i * 16 + rr;
                af[i] = *(const bf16x8*)&Al[ra * 32 + ((qr ^ ((ra >> 1) & 3)) * 8)];
            }
#pragma unroll
            for (int j = 0; j < 4; ++j) {
                const int rb = wc + j * 16 + rr;
                bfr[j] = *(const bf16x8*)&Bl[rb * 32 + ((qr ^ ((rb >> 1) & 3)) * 8)];
            }
#pragma unroll
            for (int i = 0; i < 4; ++i)
#pragma unroll
                for (int j = 0; j < 4; ++j)
                    acc[i][j] = __builtin_amdgcn_mfma_f32_16x16x32_bf16(af[i], bfr[j], acc[i][j], 0, 0, 0);
        }
        {
            bf16x8 af[4], bfr[4];
#pragma unroll
            for (int i = 0; i < 4; ++i) {
                const int ra = wr + i * 16 + rr;
                af[i] = *(const bf16x8*)&Al2[ra * 32 + ((qr ^ ((ra >> 1) & 3)) * 8)];
            }
#pragma unroll
            for (int j = 0; j < 4; ++j) {
                const int rb = wc + j * 16 + rr;
                bfr[j] = *(const bf16x8*)&Bl2[rb * 32 + ((qr ^ ((rb >> 1) & 3)) * 8)];
            }
#pragma unroll
            for (int i = 0; i < 4; ++i)
#pragma unroll
                for (int j = 0; j < 4; ++j)
                    acc[i][j] = __builtin_amdgcn_mfma_f32_16x16x32_bf16(af[i], bfr[j], acc[i][j], 0, 0, 0);
        }
        __syncthreads();   // also protects smem reuse by the epilogue on the last iter
    }

    float bev[4];
#pragma unroll
    for (int j = 0; j < 4; ++j) bev[j] = be[e * H + n0 + wc + j * 16 + rr];

    // ---- epilogue: per-wave 64x64 LDS stage (XOR col swizzle), then full-line bf16x8 stores ----
    __bf16* Cw = smem + wave * 4096;
#pragma unroll
    for (int i = 0; i < 4; ++i) {
#pragma unroll
        for (int reg = 0; reg < 4; ++reg) {
            const int row = i * 16 + qr * 4 + reg;      // C/D layout: col=lane&15, row=quad*4+reg
            const int key = (row & 7) * 8;
#pragma unroll
            for (int j = 0; j < 4; ++j) {
                const int c = j * 16 + rr;
                Cw[row * 64 + (c ^ key)] = (__bf16)(acc[i][j][reg] + bev[j]);
            }
        }
    }
    const int lrr = lane & 7, lrg = lane >> 3;
#pragma unroll
    for (int p = 0; p < 8; ++p) {
        const int row = p * 8 + lrg;
        const int rglob = m0 + wr + row;
        if (rglob < ne) {
            const int idx8 = ((lrr ^ (row & 7)) * 8);
            const bf16x8 v = *(const bf16x8*)&Cw[row * 64 + idx8];
            *(bf16x8*)(Eout + (size_t)(off + rglob) * H + n0 + wc + lrr * 8) = v;
        }
    }
}

// ---------------- combine: wave per token, out[t] = g0*row0 + g1*row1 ----------------
__global__ __launch_bounds__(256) void moe_combine(
    const __bf16* __restrict__ Eout, const int* __restrict__ cnt,
    const int* __restrict__ tsel, const float* __restrict__ tgate,
    float* __restrict__ out) {
    __shared__ int offs[NEXP];
    if (threadIdx.x < NEXP) {
        int o = 0;
        for (int i = 0; i < (int)threadIdx.x; ++i) o += cnt[i * CNTSTRIDE];
        offs[threadIdx.x] = o;
    }
    __syncthreads();
    const int wave = threadIdx.x >> 6, lane = threadIdx.x & 63;
    const int t = blockIdx.x * 4 + wave;
    const int sel0 = tsel[t * 2],  sel1 = tsel[t * 2 + 1];
    const float g0 = tgate[t * 2], g1  = tgate[t * 2 + 1];
    const int e0 = sel0 >> 13, s0 = sel0 & (CAP - 1);
    const int e1 = sel1 >> 13, s1 = sel1 & (CAP - 1);
    const __bf16* r0 = Eout + (size_t)(offs[e0] + s0) * H;
    const __bf16* r1 = Eout + (size_t)(offs[e1] + s1) * H;
    float* orow = out + (size_t)t * H;
#pragma unroll
    for (int c = 0; c < 2; ++c) {
        const int d = c * 512 + lane * 8;
        const bf16x8 a = *(const bf16x8*)(r0 + d);
        const bf16x8 b = *(const bf16x8*)(r1 + d);
        float4 o0, o1;
        o0.x = g0 * (float)a[0] + g1 * (float)b[0];
        o0.y = g0 * (float)a[1] + g1 * (float)b[1];
        o0.z = g0 * (float)a[2] + g1 * (float)b[2];
        o0.w = g0 * (float)a[3] + g1 * (float)b[3];
        o1.x = g0 * (float)a[4] + g1 * (float)b[4];
        o1.y = g0 * (float)a[5] + g1 * (float)b[5];
        o1.z = g0 * (float)a[6] + g1 * (float)b[6];
        o1.w = g0 * (float)a[7] + g1 * (float)b[7];
        *(float4*)(orow + d)     = o0;
        *(float4*)(orow + d + 4) = o1;
    }
}

extern "C" void kernel_launch(void* const* d_in, const int* in_sizes, int n_in,
                              void* d_out, int out_size, void* d_ws, size_t ws_size,
                              hipStream_t stream) {
    const float* x  = (const float*)d_in[0];
    const float* Wg = (const float*)d_in[1];
    const float* We = (const float*)d_in[2];
    const float* be = (const float*)d_in[3];
    float* out = (float*)d_out;

    char* ws = (char*)d_ws;
    __bf16* Xb   = (__bf16*)ws;
    __bf16* WeT  = (__bf16*)(ws + ((size_t)16 << 20));
    __bf16* Eout = (__bf16*)(ws + ((size_t)32 << 20));
    char*   meta = ws + ((size_t)64 << 20);
    int*    cnt  = (int*)meta;
    int*    ltok = (int*)(meta + 1024);
    int*    tsel = (int*)(meta + 1024 + (size_t)NEXP * CAP * 8);
    float*  tgat = (float*)(meta + 1024 + (size_t)NEXP * CAP * 8 + (size_t)T_TOK * 8);

    hipMemsetAsync(cnt, 0, NEXP * CNTSTRIDE * sizeof(int), stream);

    moe_transpose<<<2048, 256, 0, stream>>>(We, WeT);
    moe_route<<<512, 256, 0, stream>>>(x, Wg, Xb, cnt, ltok, tsel, tgat);
    moe_gemm<<<8 * 8 * (T_TOK / TM), 256, 0, stream>>>(Xb, WeT, be, cnt, ltok, Eout);
    moe_combine<<<T_TOK / 4, 256, 0, stream>>>(Eout, cnt, tsel, tgat, out);
}